// Round 10
// baseline (459.131 us; speedup 1.0000x reference)
//
#include <hip/hip_runtime.h>

#define NN 100000
#define NE 3200000
#define NF 512
#define NH 128
#define NC 40
#define NBIN 196      // ceil(NN/512)
#define BINW 512
#define CAP  20480    // per-bin capacity (mean 16327, +32 sigma)
#define EPB  4096     // edges per binA block

typedef __attribute__((ext_vector_type(8))) short bfrag;
typedef __attribute__((ext_vector_type(4))) float f32x4;
typedef __attribute__((ext_vector_type(8))) unsigned short u16x8;

static __device__ __forceinline__ unsigned short f2bf(float x) {
  unsigned u = __float_as_uint(x);
  u += 0x7FFF + ((u >> 16) & 1);          // RNE
  return (unsigned short)(u >> 16);
}
static __device__ __forceinline__ float bf2f(unsigned short b) {
  return __uint_as_float(((unsigned)b) << 16);
}
static __device__ __forceinline__ float bflo(unsigned u) { return __uint_as_float(u << 16); }
static __device__ __forceinline__ float bfhi(unsigned u) { return __uint_as_float(u & 0xFFFF0000u); }

// ---------------- W1 -> split-bf16 fragment layout; block 0 also zeros binfill ----------------

__global__ __launch_bounds__(256) void k_wconv(const float* __restrict__ W1,
                                               unsigned short* __restrict__ Wfh,
                                               unsigned short* __restrict__ Wfl,
                                               int* __restrict__ binfill) {
  if (blockIdx.x == 0 && threadIdx.x < NBIN) binfill[threadIdx.x] = 0;
  int i = blockIdx.x * 256 + threadIdx.x;
  int k = i >> 7, n = i & 127;
  float w = W1[i];
  unsigned short hi = f2bf(w);
  unsigned short lo = f2bf(w - bf2f(hi));
  int idx = ((k >> 3) * 128 + n) * 8 + (k & 7);
  Wfh[idx] = hi; Wfl[idx] = lo;
}

// ---------------- Pass A: bin edges by col>>9, LDS histogram + block-level reservation ----------------

__global__ __launch_bounds__(256) void k_binA(const int* __restrict__ row, const int* __restrict__ col,
                                              const float* __restrict__ w,
                                              int* __restrict__ binfill, int2* __restrict__ binned) {
  __shared__ int hist[NBIN];
  __shared__ int base[NBIN];
  int t = threadIdx.x;
  int eb = blockIdx.x * EPB;
  for (int i = t; i < NBIN; i += 256) hist[i] = 0;
  __syncthreads();
  int rk[16], bn[16], sr[16]; float wv[16];
#pragma unroll
  for (int j = 0; j < 16; ++j) {
    int e = eb + t + j * 256;
    if (e < NE) {
      int c = __builtin_nontemporal_load(col + e);
      bn[j] = c >> 9;
      sr[j] = __builtin_nontemporal_load(row + e) | ((c & 511) << 17);
      wv[j] = __builtin_nontemporal_load(w + e);
      rk[j] = atomicAdd(&hist[bn[j]], 1);
    } else bn[j] = -1;
  }
  __syncthreads();
  if (t < NBIN) { int hv = hist[t]; base[t] = hv ? atomicAdd(&binfill[t], hv) : 0; }
  __syncthreads();
#pragma unroll
  for (int j = 0; j < 16; ++j) {
    if (bn[j] >= 0) {
      int pos = base[bn[j]] + rk[j];
      if (pos < CAP) binned[(size_t)bn[j] * CAP + pos] = make_int2(sr[j], __float_as_int(wv[j]));
    }
  }
}

// ---------------- scan bin counts -> binptr; rowptr[NN]=NE ----------------

__global__ __launch_bounds__(256) void k_binscan(const int* __restrict__ binfill,
                                                 int* __restrict__ binptr, int* __restrict__ rowptr) {
  __shared__ int sm[256];
  int t = threadIdx.x;
  sm[t] = (t < NBIN) ? binfill[t] : 0;
  __syncthreads();
  for (int off = 1; off < 256; off <<= 1) {
    int a = (t >= off) ? sm[t - off] : 0;
    __syncthreads();
    sm[t] += a;
    __syncthreads();
  }
  if (t <= NBIN) binptr[t] = (t == 0) ? 0 : sm[t - 1];
  if (t == 0) rowptr[NN] = NE;
}

// ---------------- Pass B: per-bin CSR build via LDS atomics (no global atomics) ----------------

__global__ __launch_bounds__(256) void k_binB(const int* __restrict__ binfill, const int* __restrict__ binptr,
                                              const int2* __restrict__ binned, int2* __restrict__ pair,
                                              int* __restrict__ rowptr, float* __restrict__ dinv) {
  __shared__ unsigned long long pk[BINW];     // count<<42 | fixed-point weight sum
  __shared__ unsigned short lrank[CAP];
  __shared__ int lptr[BINW];
  __shared__ int sm[256];
  int t = threadIdx.x;
  int bin = blockIdx.x;
  int cnt = binfill[bin]; if (cnt > CAP) cnt = CAP;
  int bb = binptr[bin];
  pk[t] = 0ULL; pk[t + 256] = 0ULL;
  __syncthreads();
  const int2* src = binned + (size_t)bin * CAP;
  for (int i = t; i < cnt; i += 256) {
    int2 r = src[i];
    int lc = (unsigned)r.x >> 17;
    unsigned long long fw = (unsigned long long)(unsigned)(__int_as_float(r.y) * 16777216.0f + 0.5f);
    unsigned long long old = atomicAdd(&pk[lc], (1ULL << 42) | fw);
    lrank[i] = (unsigned short)(old >> 42);
  }
  __syncthreads();
  int c0 = (int)(pk[2 * t] >> 42), c1 = (int)(pk[2 * t + 1] >> 42);
  sm[t] = c0 + c1;
  __syncthreads();
  for (int off = 1; off < 256; off <<= 1) {
    int a = (t >= off) ? sm[t - off] : 0;
    __syncthreads();
    sm[t] += a;
    __syncthreads();
  }
  int excl = (t == 0) ? 0 : sm[t - 1];
  lptr[2 * t] = excl;
  lptr[2 * t + 1] = excl + c0;
  int n0 = bin * BINW + 2 * t;
  if (n0 < NN) {
    rowptr[n0] = bb + excl;
    float d = (float)(pk[2 * t] & 0x3FFFFFFFFFFULL) * (1.0f / 16777216.0f) + 1.0f;
    dinv[n0] = rsqrtf(d);
  }
  if (n0 + 1 < NN) {
    rowptr[n0 + 1] = bb + excl + c0;
    float d = (float)(pk[2 * t + 1] & 0x3FFFFFFFFFFULL) * (1.0f / 16777216.0f) + 1.0f;
    dinv[n0 + 1] = rsqrtf(d);
  }
  __syncthreads();
  for (int i = t; i < cnt; i += 256) {
    int2 r = src[i];
    int lc = (unsigned)r.x >> 17;
    int pos = bb + lptr[lc] + (int)lrank[i];
    pair[pos] = make_int2(r.x & 0x1FFFF, r.y);   // (src, raw w) — dinv folded into activations
  }
}

// ---------------- GEMM1: hx' = dinv[r] * (x @ W1); bf16 MFMA 2-term ----------------
// Wave tile 32x128: A direct global->reg (never crosses a barrier); only B LDS-staged (dbuf).

static __device__ __forceinline__ bfrag pack8(float4 lo, float4 hi) {
  union { bfrag f; unsigned short s[8]; } u;
  u.s[0] = f2bf(lo.x); u.s[1] = f2bf(lo.y); u.s[2] = f2bf(lo.z); u.s[3] = f2bf(lo.w);
  u.s[4] = f2bf(hi.x); u.s[5] = f2bf(hi.y); u.s[6] = f2bf(hi.z); u.s[7] = f2bf(hi.w);
  return u.f;
}

__global__ __launch_bounds__(256) void k_gemm1(const float* __restrict__ X,
                                               const unsigned short* __restrict__ Wfh,
                                               const unsigned short* __restrict__ Wfl,
                                               const float* __restrict__ dinv,
                                               unsigned short* __restrict__ HXb) {
  __shared__ unsigned short Bh[2][4096], Bl[2][4096];   // 32 KB
  int t = threadIdx.x;
  int lane = t & 63;
  int wid = t >> 6;
  int m0 = blockIdx.x * 128;
  int fr = lane & 15, fg = lane >> 4;
  int wrow = m0 + wid * 32;
  const float* arp0 = X + (size_t)(wrow + fr) * NF + fg * 8;        // mi=0 row
  const float* arp1 = X + (size_t)(wrow + 16 + fr) * NF + fg * 8;   // mi=1 row
  bool ok0 = (wrow + fr) < NN;
  bool ok1 = (wrow + 16 + fr) < NN;
  const float4 z4 = make_float4(0.f, 0.f, 0.f, 0.f);

  f32x4 acc[2][8];
#pragma unroll
  for (int i = 0; i < 2; ++i)
#pragma unroll
    for (int j = 0; j < 8; ++j) acc[i][j] = (f32x4)0.0f;

  // ---- prologue: ks=0 loads
  u16x8 vb0, vb1, vc0, vc1;
  float4 a00, a01, a10, a11;
  {
    const u16x8* sh = (const u16x8*)Wfh;
    const u16x8* sl = (const u16x8*)Wfl;
    vb0 = sh[t]; vb1 = sh[t + 256];
    vc0 = sl[t]; vc1 = sl[t + 256];
    a00 = ok0 ? *(const float4*)(arp0)     : z4;
    a01 = ok0 ? *(const float4*)(arp0 + 4) : z4;
    a10 = ok1 ? *(const float4*)(arp1)     : z4;
    a11 = ok1 ? *(const float4*)(arp1 + 4) : z4;
  }

  for (int ks = 0; ks < 16; ++ks) {
    int cur = ks & 1;
    // ---- stage B regs -> LDS[cur] (waits B vmcnt here)
    ((u16x8*)Bh[cur])[t] = vb0; ((u16x8*)Bh[cur])[t + 256] = vb1;
    ((u16x8*)Bl[cur])[t] = vc0; ((u16x8*)Bl[cur])[t + 256] = vc1;
    // ---- convert current A -> bf16 fragments (frees raw regs before prefetch)
    bfrag ah0 = pack8(a00, a01);
    bfrag ah1 = pack8(a10, a11);
    __syncthreads();
    // ---- prefetch ks+1 AFTER the barrier (not drained until next barrier)
    if (ks < 15) {
      const u16x8* sh = (const u16x8*)(Wfh + (size_t)(ks + 1) * 4096);
      const u16x8* sl = (const u16x8*)(Wfl + (size_t)(ks + 1) * 4096);
      vb0 = sh[t]; vb1 = sh[t + 256];
      vc0 = sl[t]; vc1 = sl[t + 256];
      int ko = (ks + 1) * 32;
      a00 = ok0 ? *(const float4*)(arp0 + ko)     : z4;
      a01 = ok0 ? *(const float4*)(arp0 + ko + 4) : z4;
      a10 = ok1 ? *(const float4*)(arp1 + ko)     : z4;
      a11 = ok1 ? *(const float4*)(arp1 + ko + 4) : z4;
    }
    // ---- B fragments from LDS[cur] + MFMA (full N per wave)
#pragma unroll
    for (int nt = 0; nt < 8; ++nt) {
      int idx = (fg * 128 + nt * 16 + fr) * 8;
      bfrag bh = *(bfrag*)&Bh[cur][idx];
      bfrag bl = *(bfrag*)&Bl[cur][idx];
      acc[0][nt] = __builtin_amdgcn_mfma_f32_16x16x32_bf16(ah0, bh, acc[0][nt], 0, 0, 0);
      acc[1][nt] = __builtin_amdgcn_mfma_f32_16x16x32_bf16(ah1, bh, acc[1][nt], 0, 0, 0);
      acc[0][nt] = __builtin_amdgcn_mfma_f32_16x16x32_bf16(ah0, bl, acc[0][nt], 0, 0, 0);
      acc[1][nt] = __builtin_amdgcn_mfma_f32_16x16x32_bf16(ah1, bl, acc[1][nt], 0, 0, 0);
    }
    // no trailing barrier: next iteration writes the OTHER buffer
  }
  // ---- epilogue: D row = wrow + mi*16 + fg*4 + q, col = nt*16 + fr
#pragma unroll
  for (int mi = 0; mi < 2; ++mi) {
    int rb = wrow + mi * 16 + fg * 4;
#pragma unroll
    for (int q = 0; q < 4; ++q) {
      int r = rb + q;
      if (r < NN) {
        float dv = dinv[r];
#pragma unroll
        for (int nt = 0; nt < 8; ++nt)
          __builtin_nontemporal_store(f2bf(dv * acc[mi][nt][q]),
                                      HXb + (size_t)r * NH + nt * 16 + fr);
      }
    }
  }
}

// ---------------- agg1: 16 lanes/row, 4 edges/step, 16-edge main loop ----------------
// h = relu(dinv_c*(sum_e w*hx'[src] + hx'[c]) + b1)

#define FMA8(n, v)                                            \
  { unsigned uu[4] = {(v).x, (v).y, (v).z, (v).w};            \
    _Pragma("unroll")                                         \
    for (int q = 0; q < 4; ++q) {                             \
      ax[q] = fmaf((n), bflo(uu[q]), ax[q]);                  \
      ay[q] = fmaf((n), bfhi(uu[q]), ay[q]);                  \
    } }

__global__ __launch_bounds__(256) void k_agg1(const int* __restrict__ rowptr, const int2* __restrict__ pair,
                                              const unsigned* __restrict__ hxb, const float* __restrict__ dinv,
                                              const float* __restrict__ b1, unsigned* __restrict__ hb) {
  int wid = (blockIdx.x * 256 + threadIdx.x) >> 6;
  int lane = threadIdx.x & 63;
  if (wid >= NN) return;
  int sub = lane >> 4, fl = lane & 15;
  int beg = rowptr[wid], end = rowptr[wid + 1];
  const uint4* hx4 = (const uint4*)hxb;            // row = 16 uint4 (256 B)
  const long long* pr = (const long long*)pair;
  float ax[4] = {0.f, 0.f, 0.f, 0.f}, ay[4] = {0.f, 0.f, 0.f, 0.f};
  int e = beg;
  for (; e + 16 <= end; e += 16) {
    long long r0 = pr[e + sub];
    long long r1 = pr[e + 4 + sub];
    long long r2 = pr[e + 8 + sub];
    long long r3 = pr[e + 12 + sub];
    uint4 v0 = hx4[(size_t)(unsigned)(r0 & 0x1FFFF) * 16 + fl];
    uint4 v1 = hx4[(size_t)(unsigned)(r1 & 0x1FFFF) * 16 + fl];
    uint4 v2 = hx4[(size_t)(unsigned)(r2 & 0x1FFFF) * 16 + fl];
    uint4 v3 = hx4[(size_t)(unsigned)(r3 & 0x1FFFF) * 16 + fl];
    float n0 = __int_as_float((int)(r0 >> 32));
    float n1 = __int_as_float((int)(r1 >> 32));
    float n2 = __int_as_float((int)(r2 >> 32));
    float n3 = __int_as_float((int)(r3 >> 32));
    FMA8(n0, v0);
    FMA8(n1, v1);
    FMA8(n2, v2);
    FMA8(n3, v3);
  }
  for (; e + 8 <= end; e += 8) {
    long long r0 = pr[e + sub];
    long long r1 = pr[e + 4 + sub];
    uint4 v0 = hx4[(size_t)(unsigned)(r0 & 0x1FFFF) * 16 + fl];
    uint4 v1 = hx4[(size_t)(unsigned)(r1 & 0x1FFFF) * 16 + fl];
    float n0 = __int_as_float((int)(r0 >> 32));
    float n1 = __int_as_float((int)(r1 >> 32));
    FMA8(n0, v0);
    FMA8(n1, v1);
  }
  for (; e < end; e += 4) {
    int idx = e + sub;
    bool ok = idx < end;
    long long r0 = ok ? pr[idx] : 0;
    unsigned s = ok ? (unsigned)(r0 & 0x1FFFF) : (unsigned)wid;
    float n0 = ok ? __int_as_float((int)(r0 >> 32)) : 0.f;
    uint4 v0 = hx4[(size_t)s * 16 + fl];
    FMA8(n0, v0);
  }
  if (sub == 0) {                                   // self term, weight 1
    uint4 ov = hx4[(size_t)wid * 16 + fl];
    FMA8(1.0f, ov);
  }
#pragma unroll
  for (int q = 0; q < 4; ++q) {
    ax[q] += __shfl_xor(ax[q], 16, 64); ay[q] += __shfl_xor(ay[q], 16, 64);
    ax[q] += __shfl_xor(ax[q], 32, 64); ay[q] += __shfl_xor(ay[q], 32, 64);
  }
  if (sub == 0) {
    float di = dinv[wid];
    float4 bA = ((const float4*)b1)[fl * 2];
    float4 bB = ((const float4*)b1)[fl * 2 + 1];
    float bxs[4] = {bA.x, bA.z, bB.x, bB.z};
    float bys[4] = {bA.y, bA.w, bB.y, bB.w};
    unsigned o[4];
#pragma unroll
    for (int q = 0; q < 4; ++q) {
      float rx = fmaxf(fmaf(di, ax[q], bxs[q]), 0.f);
      float ry = fmaxf(fmaf(di, ay[q], bys[q]), 0.f);
      o[q] = (unsigned)f2bf(rx) | ((unsigned)f2bf(ry) << 16);
    }
    ((uint4*)hb)[(size_t)wid * 16 + fl] = make_uint4(o[0], o[1], o[2], o[3]);
  }
}

// ---------------- GEMM2: h2' = dinv[r] * (h @ W2)   [bf16 in, bf16-padded64 out] ----------------

__global__ __launch_bounds__(256) void k_gemm2(const unsigned* __restrict__ hb, const float* __restrict__ W2,
                                               const float* __restrict__ dinv,
                                               unsigned short* __restrict__ H2b) {
  __shared__ float Hs[32][132];
  __shared__ float Ws[NH * NC];
  int t = threadIdx.x;
  int m0 = blockIdx.x * 32;
  {
    int r = t >> 3, cb = (t & 7) * 8;
    int rowi = m0 + r;
    if (rowi < NN) {
      uint4 a = *(const uint4*)(hb + (size_t)rowi * 64 + cb);
      uint4 b = *(const uint4*)(hb + (size_t)rowi * 64 + cb + 4);
      unsigned u[8] = {a.x, a.y, a.z, a.w, b.x, b.y, b.z, b.w};
#pragma unroll
      for (int j = 0; j < 8; ++j) {
        Hs[r][cb * 2 + j * 2]     = bflo(u[j]);
        Hs[r][cb * 2 + j * 2 + 1] = bfhi(u[j]);
      }
    } else {
#pragma unroll
      for (int j = 0; j < 16; ++j) Hs[r][cb * 2 + j] = 0.f;
    }
  }
  for (int i = t; i < NH * NC; i += 256) Ws[i] = W2[i];
  __syncthreads();
  int r = t >> 3, c0 = (t & 7) * 5;
  float acc[5] = {0.f, 0.f, 0.f, 0.f, 0.f};
#pragma unroll 4
  for (int k = 0; k < NH; ++k) {
    float hv = Hs[r][k];
#pragma unroll
    for (int j = 0; j < 5; ++j) acc[j] = fmaf(hv, Ws[k * NC + c0 + j], acc[j]);
  }
  int rowi = m0 + r;
  if (rowi < NN) {
    float dv = dinv[rowi];
#pragma unroll
    for (int j = 0; j < 5; ++j)
      __builtin_nontemporal_store(f2bf(dv * acc[j]), H2b + (size_t)rowi * 64 + c0 + j);
    int prr = t & 7;
    if (prr < 3) {
#pragma unroll
      for (int j = 0; j < 8; ++j)
        __builtin_nontemporal_store((unsigned short)0, H2b + (size_t)rowi * 64 + 40 + prr * 8 + j);
    }
  }
}

// ---------------- agg2: 16 lanes/row, 4 edges/step, 16-edge main loop ----------------
// out = dinv_c*(sum_e w*h2'[src] + h2'[c]) + b2

#define FMA4(n, v)                                            \
  { unsigned uu[2] = {(v).x, (v).y};                          \
    _Pragma("unroll")                                         \
    for (int q = 0; q < 2; ++q) {                             \
      ax[q] = fmaf((n), bflo(uu[q]), ax[q]);                  \
      ay[q] = fmaf((n), bfhi(uu[q]), ay[q]);                  \
    } }

__global__ __launch_bounds__(256) void k_agg2(const int* __restrict__ rowptr, const int2* __restrict__ pair,
                                              const unsigned* __restrict__ h2u,
                                              const float* __restrict__ dinv,
                                              const float* __restrict__ b2, float* __restrict__ out) {
  int wid = (blockIdx.x * 256 + threadIdx.x) >> 6;
  int lane = threadIdx.x & 63;
  if (wid >= NN) return;
  int sub = lane >> 4, fl = lane & 15;
  int beg = rowptr[wid], end = rowptr[wid + 1];
  const uint2* h4 = (const uint2*)h2u;              // row = 16 uint2 (128 B)
  const long long* pr = (const long long*)pair;
  float ax[2] = {0.f, 0.f}, ay[2] = {0.f, 0.f};
  int e = beg;
  for (; e + 16 <= end; e += 16) {
    long long r0 = pr[e + sub];
    long long r1 = pr[e + 4 + sub];
    long long r2 = pr[e + 8 + sub];
    long long r3 = pr[e + 12 + sub];
    uint2 v0 = h4[(size_t)(unsigned)(r0 & 0x1FFFF) * 16 + fl];
    uint2 v1 = h4[(size_t)(unsigned)(r1 & 0x1FFFF) * 16 + fl];
    uint2 v2 = h4[(size_t)(unsigned)(r2 & 0x1FFFF) * 16 + fl];
    uint2 v3 = h4[(size_t)(unsigned)(r3 & 0x1FFFF) * 16 + fl];
    float n0 = __int_as_float((int)(r0 >> 32));
    float n1 = __int_as_float((int)(r1 >> 32));
    float n2 = __int_as_float((int)(r2 >> 32));
    float n3 = __int_as_float((int)(r3 >> 32));
    FMA4(n0, v0);
    FMA4(n1, v1);
    FMA4(n2, v2);
    FMA4(n3, v3);
  }
  for (; e + 8 <= end; e += 8) {
    long long r0 = pr[e + sub];
    long long r1 = pr[e + 4 + sub];
    uint2 v0 = h4[(size_t)(unsigned)(r0 & 0x1FFFF) * 16 + fl];
    uint2 v1 = h4[(size_t)(unsigned)(r1 & 0x1FFFF) * 16 + fl];
    float n0 = __int_as_float((int)(r0 >> 32));
    float n1 = __int_as_float((int)(r1 >> 32));
    FMA4(n0, v0);
    FMA4(n1, v1);
  }
  for (; e < end; e += 4) {
    int idx = e + sub;
    bool ok = idx < end;
    long long r0 = ok ? pr[idx] : 0;
    unsigned s = ok ? (unsigned)(r0 & 0x1FFFF) : (unsigned)wid;
    float n0 = ok ? __int_as_float((int)(r0 >> 32)) : 0.f;
    uint2 v0 = h4[(size_t)s * 16 + fl];
    FMA4(n0, v0);
  }
  if (sub == 0) {                                   // self term
    uint2 ov = h4[(size_t)wid * 16 + fl];
    FMA4(1.0f, ov);
  }
#pragma unroll
  for (int q = 0; q < 2; ++q) {
    ax[q] += __shfl_xor(ax[q], 16, 64); ay[q] += __shfl_xor(ay[q], 16, 64);
    ax[q] += __shfl_xor(ax[q], 32, 64); ay[q] += __shfl_xor(ay[q], 32, 64);
  }
  if (sub == 0 && fl < 10) {
    float di = dinv[wid];
    float4 bv = ((const float4*)b2)[fl];
    float4 o = make_float4(fmaf(di, ax[0], bv.x), fmaf(di, ay[0], bv.y),
                           fmaf(di, ax[1], bv.z), fmaf(di, ay[1], bv.w));
    *(float4*)(out + (size_t)wid * NC + fl * 4) = o;
  }
}

// ---------------- host launch ----------------

extern "C" void kernel_launch(void* const* d_in, const int* in_sizes, int n_in,
                              void* d_out, int out_size, void* d_ws, size_t ws_size,
                              hipStream_t stream) {
  const float* x  = (const float*)d_in[0];
  const int*   ei = (const int*)d_in[1];
  const float* ew = (const float*)d_in[2];
  const float* W1 = (const float*)d_in[3];
  const float* b1 = (const float*)d_in[4];
  const float* W2 = (const float*)d_in[5];
  const float* b2 = (const float*)d_in[6];
  float* out = (float*)d_out;
  const int* row = ei;
  const int* col = ei + NE;

  char* ws = (char*)d_ws;
  size_t o = 0;
  auto alloc = [&](size_t bytes) -> void* {
    void* p = ws + o;
    o += (bytes + 255) & ~(size_t)255;
    return p;
  };
  float* dinv    = (float*)alloc((size_t)NN * 4);
  int*   rowptr  = (int*)alloc((size_t)(NN + 1) * 4);
  int*   binfill = (int*)alloc(1024);
  int*   binptr  = (int*)alloc(1024);
  int2*  pair    = (int2*)alloc((size_t)NE * 8);
  unsigned short* Wfh = (unsigned short*)alloc((size_t)NF * NH * 2);
  unsigned short* Wfl = (unsigned short*)alloc((size_t)NF * NH * 2);
  unsigned short* hxb = (unsigned short*)alloc((size_t)NN * NH * 2);
  unsigned*       hb  = (unsigned*)alloc((size_t)NN * NH * 2);
  int2*  binned  = (int2*)alloc((size_t)NBIN * CAP * 8);
  unsigned short* h2b = (unsigned short*)hxb;   // hxb dead after k_agg1

  k_wconv<<<(NF * NH) / 256, 256, 0, stream>>>(W1, Wfh, Wfl, binfill);
  k_binA<<<(NE + EPB - 1) / EPB, 256, 0, stream>>>(row, col, ew, binfill, binned);
  k_binscan<<<1, 256, 0, stream>>>(binfill, binptr, rowptr);
  k_binB<<<NBIN, 256, 0, stream>>>(binfill, binptr, binned, pair, rowptr, dinv);
  k_gemm1<<<(NN + 127) / 128, 256, 0, stream>>>(x, Wfh, Wfl, dinv, hxb);
  k_agg1<<<(NN * 64) / 256, 256, 0, stream>>>(rowptr, pair, (const unsigned*)hxb, dinv, b1, hb);
  k_gemm2<<<(NN + 31) / 32, 256, 0, stream>>>(hb, W2, dinv, h2b);
  k_agg2<<<(NN * 64) / 256, 256, 0, stream>>>(rowptr, pair, (const unsigned*)h2b, dinv, b2, out);
}

// Round 11
// 401.416 us; speedup vs baseline: 1.1438x; 1.1438x over previous
//
#include <hip/hip_runtime.h>

#define NN 100000
#define NE 3200000
#define NF 512
#define NH 128
#define NC 40
#define NBIN 196      // ceil(NN/512)
#define BINW 512
#define CAP  20480    // per-bin capacity (mean 16327, +32 sigma)
#define EPB  4096     // edges per binA block

typedef __attribute__((ext_vector_type(8))) short bfrag;
typedef __attribute__((ext_vector_type(4))) float f32x4;
typedef __attribute__((ext_vector_type(8))) unsigned short u16x8;

static __device__ __forceinline__ unsigned short f2bf(float x) {
  unsigned u = __float_as_uint(x);
  u += 0x7FFF + ((u >> 16) & 1);          // RNE
  return (unsigned short)(u >> 16);
}
static __device__ __forceinline__ float bf2f(unsigned short b) {
  return __uint_as_float(((unsigned)b) << 16);
}
static __device__ __forceinline__ float bflo(unsigned u) { return __uint_as_float(u << 16); }
static __device__ __forceinline__ float bfhi(unsigned u) { return __uint_as_float(u & 0xFFFF0000u); }

// ---------------- W1 -> split-bf16 fragment layout; block 0 also zeros binfill ----------------

__global__ __launch_bounds__(256) void k_wconv(const float* __restrict__ W1,
                                               unsigned short* __restrict__ Wfh,
                                               unsigned short* __restrict__ Wfl,
                                               int* __restrict__ binfill) {
  if (blockIdx.x == 0 && threadIdx.x < NBIN) binfill[threadIdx.x] = 0;
  int i = blockIdx.x * 256 + threadIdx.x;
  int k = i >> 7, n = i & 127;
  float w = W1[i];
  unsigned short hi = f2bf(w);
  unsigned short lo = f2bf(w - bf2f(hi));
  int idx = ((k >> 3) * 128 + n) * 8 + (k & 7);
  Wfh[idx] = hi; Wfl[idx] = lo;
}

// ---------------- Pass A: bin edges by col>>9, LDS histogram + block-level reservation ----------------

__global__ __launch_bounds__(256) void k_binA(const int* __restrict__ row, const int* __restrict__ col,
                                              const float* __restrict__ w,
                                              int* __restrict__ binfill, int2* __restrict__ binned) {
  __shared__ int hist[NBIN];
  __shared__ int base[NBIN];
  int t = threadIdx.x;
  int eb = blockIdx.x * EPB;
  for (int i = t; i < NBIN; i += 256) hist[i] = 0;
  __syncthreads();
  int rk[16], bn[16], sr[16]; float wv[16];
#pragma unroll
  for (int j = 0; j < 16; ++j) {
    int e = eb + t + j * 256;
    if (e < NE) {
      int c = __builtin_nontemporal_load(col + e);
      bn[j] = c >> 9;
      sr[j] = __builtin_nontemporal_load(row + e) | ((c & 511) << 17);
      wv[j] = __builtin_nontemporal_load(w + e);
      rk[j] = atomicAdd(&hist[bn[j]], 1);
    } else bn[j] = -1;
  }
  __syncthreads();
  if (t < NBIN) { int hv = hist[t]; base[t] = hv ? atomicAdd(&binfill[t], hv) : 0; }
  __syncthreads();
#pragma unroll
  for (int j = 0; j < 16; ++j) {
    if (bn[j] >= 0) {
      int pos = base[bn[j]] + rk[j];
      if (pos < CAP) binned[(size_t)bn[j] * CAP + pos] = make_int2(sr[j], __float_as_int(wv[j]));
    }
  }
}

// ---------------- scan bin counts -> binptr; rowptr[NN]=NE ----------------

__global__ __launch_bounds__(256) void k_binscan(const int* __restrict__ binfill,
                                                 int* __restrict__ binptr, int* __restrict__ rowptr) {
  __shared__ int sm[256];
  int t = threadIdx.x;
  sm[t] = (t < NBIN) ? binfill[t] : 0;
  __syncthreads();
  for (int off = 1; off < 256; off <<= 1) {
    int a = (t >= off) ? sm[t - off] : 0;
    __syncthreads();
    sm[t] += a;
    __syncthreads();
  }
  if (t <= NBIN) binptr[t] = (t == 0) ? 0 : sm[t - 1];
  if (t == 0) rowptr[NN] = NE;
}

// ---------------- Pass B: per-bin CSR build via LDS atomics (no global atomics) ----------------

__global__ __launch_bounds__(256) void k_binB(const int* __restrict__ binfill, const int* __restrict__ binptr,
                                              const int2* __restrict__ binned, int2* __restrict__ pair,
                                              int* __restrict__ rowptr, float* __restrict__ dinv) {
  __shared__ unsigned long long pk[BINW];     // count<<42 | fixed-point weight sum
  __shared__ unsigned short lrank[CAP];
  __shared__ int lptr[BINW];
  __shared__ int sm[256];
  int t = threadIdx.x;
  int bin = blockIdx.x;
  int cnt = binfill[bin]; if (cnt > CAP) cnt = CAP;
  int bb = binptr[bin];
  pk[t] = 0ULL; pk[t + 256] = 0ULL;
  __syncthreads();
  const int2* src = binned + (size_t)bin * CAP;
  for (int i = t; i < cnt; i += 256) {
    int2 r = src[i];
    int lc = (unsigned)r.x >> 17;
    unsigned long long fw = (unsigned long long)(unsigned)(__int_as_float(r.y) * 16777216.0f + 0.5f);
    unsigned long long old = atomicAdd(&pk[lc], (1ULL << 42) | fw);
    lrank[i] = (unsigned short)(old >> 42);
  }
  __syncthreads();
  int c0 = (int)(pk[2 * t] >> 42), c1 = (int)(pk[2 * t + 1] >> 42);
  sm[t] = c0 + c1;
  __syncthreads();
  for (int off = 1; off < 256; off <<= 1) {
    int a = (t >= off) ? sm[t - off] : 0;
    __syncthreads();
    sm[t] += a;
    __syncthreads();
  }
  int excl = (t == 0) ? 0 : sm[t - 1];
  lptr[2 * t] = excl;
  lptr[2 * t + 1] = excl + c0;
  int n0 = bin * BINW + 2 * t;
  if (n0 < NN) {
    rowptr[n0] = bb + excl;
    float d = (float)(pk[2 * t] & 0x3FFFFFFFFFFULL) * (1.0f / 16777216.0f) + 1.0f;
    dinv[n0] = rsqrtf(d);
  }
  if (n0 + 1 < NN) {
    rowptr[n0 + 1] = bb + excl + c0;
    float d = (float)(pk[2 * t + 1] & 0x3FFFFFFFFFFULL) * (1.0f / 16777216.0f) + 1.0f;
    dinv[n0 + 1] = rsqrtf(d);
  }
  __syncthreads();
  for (int i = t; i < cnt; i += 256) {
    int2 r = src[i];
    int lc = (unsigned)r.x >> 17;
    int pos = bb + lptr[lc] + (int)lrank[i];
    pair[pos] = make_int2(r.x & 0x1FFFF, r.y);   // (src, raw w) — dinv folded into activations
  }
}

// ---------------- GEMM1: hx' = dinv[r] * (x @ W1); bf16 MFMA 2-term ----------------
// BM=64 tile (grid 1563) for TLP; round-8 two-barrier structure; 20 KB LDS.

__global__ __launch_bounds__(256) void k_gemm1(const float* __restrict__ X,
                                               const unsigned short* __restrict__ Wfh,
                                               const unsigned short* __restrict__ Wfl,
                                               const float* __restrict__ dinv,
                                               unsigned short* __restrict__ HXb) {
  __shared__ unsigned short Ah[2048], Bh[4096], Bl[4096];   // 20 KB
  int t = threadIdx.x;
  int lane = t & 63;
  int wid = t >> 6;
  int m0 = blockIdx.x * 64;
  int sm = t & 63;            // staging row
  int skh = t >> 6;           // k-chunk (8 f32 each)
  const float* xrow = X + (size_t)(m0 + sm) * NF + skh * 8;
  bool mok = (m0 + sm) < NN;
  int wm = wid >> 1, wn = wid & 1;
  int mb = wm * 32, nb = wn * 64;
  int fr = lane & 15, fg = lane >> 4;

  f32x4 acc[2][4];
#pragma unroll
  for (int i = 0; i < 2; ++i)
#pragma unroll
    for (int j = 0; j < 4; ++j) acc[i][j] = (f32x4)0.0f;

  for (int ks = 0; ks < 16; ++ks) {
    // ---- issue global loads (B slabs + 8 f32 of A per thread)
    const u16x8* sh = (const u16x8*)(Wfh + (size_t)ks * 4096);
    const u16x8* sl = (const u16x8*)(Wfl + (size_t)ks * 4096);
    u16x8 b0 = sh[t], b1 = sh[t + 256];
    u16x8 c0 = sl[t], c1 = sl[t + 256];
    float4 xv0 = mok ? *(const float4*)(xrow + ks * 32)     : make_float4(0.f, 0.f, 0.f, 0.f);
    float4 xv1 = mok ? *(const float4*)(xrow + ks * 32 + 4) : make_float4(0.f, 0.f, 0.f, 0.f);
    // ---- convert A (hi only) and write LDS: layout [kb=k>>3][64 rows][8]
#pragma unroll
    for (int q = 0; q < 2; ++q) {
      float4 xq = q ? xv1 : xv0;
      float f[4] = {xq.x, xq.y, xq.z, xq.w};
      unsigned short h[4];
#pragma unroll
      for (int j = 0; j < 4; ++j) h[j] = f2bf(f[j]);
      int base = (skh * 64 + sm) * 8 + q * 4;
      uint2 hv = make_uint2((unsigned)h[0] | ((unsigned)h[1] << 16),
                            (unsigned)h[2] | ((unsigned)h[3] << 16));
      *(uint2*)&Ah[base] = hv;
    }
    ((u16x8*)Bh)[t] = b0; ((u16x8*)Bh)[t + 256] = b1;
    ((u16x8*)Bl)[t] = c0; ((u16x8*)Bl)[t + 256] = c1;
    __syncthreads();
    // ---- fragments from LDS
    bfrag ah[2], bh[4], bl[4];
#pragma unroll
    for (int mi = 0; mi < 2; ++mi)
      ah[mi] = *(bfrag*)&Ah[(fg * 64 + mb + mi * 16 + fr) * 8];
#pragma unroll
    for (int nt = 0; nt < 4; ++nt) {
      int idx = (fg * 128 + nb + nt * 16 + fr) * 8;
      bh[nt] = *(bfrag*)&Bh[idx];
      bl[nt] = *(bfrag*)&Bl[idx];
    }
#pragma unroll
    for (int mi = 0; mi < 2; ++mi)
#pragma unroll
      for (int nt = 0; nt < 4; ++nt) {
        acc[mi][nt] = __builtin_amdgcn_mfma_f32_16x16x32_bf16(ah[mi], bh[nt], acc[mi][nt], 0, 0, 0);
        acc[mi][nt] = __builtin_amdgcn_mfma_f32_16x16x32_bf16(ah[mi], bl[nt], acc[mi][nt], 0, 0, 0);
      }
    __syncthreads();
  }
  // ---- epilogue: D row = m0 + mb + mi*16 + fg*4 + q, col = nb + nt*16 + fr
#pragma unroll
  for (int mi = 0; mi < 2; ++mi) {
    int rb = m0 + mb + mi * 16 + fg * 4;
#pragma unroll
    for (int q = 0; q < 4; ++q) {
      int r = rb + q;
      if (r < NN) {
        float dv = dinv[r];
#pragma unroll
        for (int nt = 0; nt < 4; ++nt) {
          int c = nb + nt * 16 + fr;
          __builtin_nontemporal_store(f2bf(dv * acc[mi][nt][q]), HXb + (size_t)r * NH + c);
        }
      }
    }
  }
}

// ---------------- agg1: 16 lanes/row, 4 edges/step, 16-edge main loop ----------------
// h = relu(dinv_c*(sum_e w*hx'[src] + hx'[c]) + b1)

#define FMA8(n, v)                                            \
  { unsigned uu[4] = {(v).x, (v).y, (v).z, (v).w};            \
    _Pragma("unroll")                                         \
    for (int q = 0; q < 4; ++q) {                             \
      ax[q] = fmaf((n), bflo(uu[q]), ax[q]);                  \
      ay[q] = fmaf((n), bfhi(uu[q]), ay[q]);                  \
    } }

__global__ __launch_bounds__(256) void k_agg1(const int* __restrict__ rowptr, const int2* __restrict__ pair,
                                              const unsigned* __restrict__ hxb, const float* __restrict__ dinv,
                                              const float* __restrict__ b1, unsigned* __restrict__ hb) {
  int wid = (blockIdx.x * 256 + threadIdx.x) >> 6;
  int lane = threadIdx.x & 63;
  if (wid >= NN) return;
  int sub = lane >> 4, fl = lane & 15;
  int beg = rowptr[wid], end = rowptr[wid + 1];
  const uint4* hx4 = (const uint4*)hxb;            // row = 16 uint4 (256 B)
  const long long* pr = (const long long*)pair;
  float ax[4] = {0.f, 0.f, 0.f, 0.f}, ay[4] = {0.f, 0.f, 0.f, 0.f};
  int e = beg;
  for (; e + 16 <= end; e += 16) {
    long long r0 = pr[e + sub];
    long long r1 = pr[e + 4 + sub];
    long long r2 = pr[e + 8 + sub];
    long long r3 = pr[e + 12 + sub];
    uint4 v0 = hx4[(size_t)(unsigned)(r0 & 0x1FFFF) * 16 + fl];
    uint4 v1 = hx4[(size_t)(unsigned)(r1 & 0x1FFFF) * 16 + fl];
    uint4 v2 = hx4[(size_t)(unsigned)(r2 & 0x1FFFF) * 16 + fl];
    uint4 v3 = hx4[(size_t)(unsigned)(r3 & 0x1FFFF) * 16 + fl];
    float n0 = __int_as_float((int)(r0 >> 32));
    float n1 = __int_as_float((int)(r1 >> 32));
    float n2 = __int_as_float((int)(r2 >> 32));
    float n3 = __int_as_float((int)(r3 >> 32));
    FMA8(n0, v0);
    FMA8(n1, v1);
    FMA8(n2, v2);
    FMA8(n3, v3);
  }
  for (; e + 8 <= end; e += 8) {
    long long r0 = pr[e + sub];
    long long r1 = pr[e + 4 + sub];
    uint4 v0 = hx4[(size_t)(unsigned)(r0 & 0x1FFFF) * 16 + fl];
    uint4 v1 = hx4[(size_t)(unsigned)(r1 & 0x1FFFF) * 16 + fl];
    float n0 = __int_as_float((int)(r0 >> 32));
    float n1 = __int_as_float((int)(r1 >> 32));
    FMA8(n0, v0);
    FMA8(n1, v1);
  }
  for (; e < end; e += 4) {
    int idx = e + sub;
    bool ok = idx < end;
    long long r0 = ok ? pr[idx] : 0;
    unsigned s = ok ? (unsigned)(r0 & 0x1FFFF) : (unsigned)wid;
    float n0 = ok ? __int_as_float((int)(r0 >> 32)) : 0.f;
    uint4 v0 = hx4[(size_t)s * 16 + fl];
    FMA8(n0, v0);
  }
  if (sub == 0) {                                   // self term, weight 1
    uint4 ov = hx4[(size_t)wid * 16 + fl];
    FMA8(1.0f, ov);
  }
#pragma unroll
  for (int q = 0; q < 4; ++q) {
    ax[q] += __shfl_xor(ax[q], 16, 64); ay[q] += __shfl_xor(ay[q], 16, 64);
    ax[q] += __shfl_xor(ax[q], 32, 64); ay[q] += __shfl_xor(ay[q], 32, 64);
  }
  if (sub == 0) {
    float di = dinv[wid];
    float4 bA = ((const float4*)b1)[fl * 2];
    float4 bB = ((const float4*)b1)[fl * 2 + 1];
    float bxs[4] = {bA.x, bA.z, bB.x, bB.z};
    float bys[4] = {bA.y, bA.w, bB.y, bB.w};
    unsigned o[4];
#pragma unroll
    for (int q = 0; q < 4; ++q) {
      float rx = fmaxf(fmaf(di, ax[q], bxs[q]), 0.f);
      float ry = fmaxf(fmaf(di, ay[q], bys[q]), 0.f);
      o[q] = (unsigned)f2bf(rx) | ((unsigned)f2bf(ry) << 16);
    }
    ((uint4*)hb)[(size_t)wid * 16 + fl] = make_uint4(o[0], o[1], o[2], o[3]);
  }
}

// ---------------- GEMM2: h2' = dinv[r] * (h @ W2)   [bf16 in, bf16-padded64 out] ----------------

__global__ __launch_bounds__(256) void k_gemm2(const unsigned* __restrict__ hb, const float* __restrict__ W2,
                                               const float* __restrict__ dinv,
                                               unsigned short* __restrict__ H2b) {
  __shared__ float Hs[32][132];
  __shared__ float Ws[NH * NC];
  int t = threadIdx.x;
  int m0 = blockIdx.x * 32;
  {
    int r = t >> 3, cb = (t & 7) * 8;
    int rowi = m0 + r;
    if (rowi < NN) {
      uint4 a = *(const uint4*)(hb + (size_t)rowi * 64 + cb);
      uint4 b = *(const uint4*)(hb + (size_t)rowi * 64 + cb + 4);
      unsigned u[8] = {a.x, a.y, a.z, a.w, b.x, b.y, b.z, b.w};
#pragma unroll
      for (int j = 0; j < 8; ++j) {
        Hs[r][cb * 2 + j * 2]     = bflo(u[j]);
        Hs[r][cb * 2 + j * 2 + 1] = bfhi(u[j]);
      }
    } else {
#pragma unroll
      for (int j = 0; j < 16; ++j) Hs[r][cb * 2 + j] = 0.f;
    }
  }
  for (int i = t; i < NH * NC; i += 256) Ws[i] = W2[i];
  __syncthreads();
  int r = t >> 3, c0 = (t & 7) * 5;
  float acc[5] = {0.f, 0.f, 0.f, 0.f, 0.f};
#pragma unroll 4
  for (int k = 0; k < NH; ++k) {
    float hv = Hs[r][k];
#pragma unroll
    for (int j = 0; j < 5; ++j) acc[j] = fmaf(hv, Ws[k * NC + c0 + j], acc[j]);
  }
  int rowi = m0 + r;
  if (rowi < NN) {
    float dv = dinv[rowi];
#pragma unroll
    for (int j = 0; j < 5; ++j)
      __builtin_nontemporal_store(f2bf(dv * acc[j]), H2b + (size_t)rowi * 64 + c0 + j);
    int prr = t & 7;
    if (prr < 3) {
#pragma unroll
      for (int j = 0; j < 8; ++j)
        __builtin_nontemporal_store((unsigned short)0, H2b + (size_t)rowi * 64 + 40 + prr * 8 + j);
    }
  }
}

// ---------------- agg2: 16 lanes/row, 4 edges/step, 16-edge main loop ----------------
// out = dinv_c*(sum_e w*h2'[src] + h2'[c]) + b2

#define FMA4(n, v)                                            \
  { unsigned uu[2] = {(v).x, (v).y};                          \
    _Pragma("unroll")                                         \
    for (int q = 0; q < 2; ++q) {                             \
      ax[q] = fmaf((n), bflo(uu[q]), ax[q]);                  \
      ay[q] = fmaf((n), bfhi(uu[q]), ay[q]);                  \
    } }

__global__ __launch_bounds__(256) void k_agg2(const int* __restrict__ rowptr, const int2* __restrict__ pair,
                                              const unsigned* __restrict__ h2u,
                                              const float* __restrict__ dinv,
                                              const float* __restrict__ b2, float* __restrict__ out) {
  int wid = (blockIdx.x * 256 + threadIdx.x) >> 6;
  int lane = threadIdx.x & 63;
  if (wid >= NN) return;
  int sub = lane >> 4, fl = lane & 15;
  int beg = rowptr[wid], end = rowptr[wid + 1];
  const uint2* h4 = (const uint2*)h2u;              // row = 16 uint2 (128 B)
  const long long* pr = (const long long*)pair;
  float ax[2] = {0.f, 0.f}, ay[2] = {0.f, 0.f};
  int e = beg;
  for (; e + 16 <= end; e += 16) {
    long long r0 = pr[e + sub];
    long long r1 = pr[e + 4 + sub];
    long long r2 = pr[e + 8 + sub];
    long long r3 = pr[e + 12 + sub];
    uint2 v0 = h4[(size_t)(unsigned)(r0 & 0x1FFFF) * 16 + fl];
    uint2 v1 = h4[(size_t)(unsigned)(r1 & 0x1FFFF) * 16 + fl];
    uint2 v2 = h4[(size_t)(unsigned)(r2 & 0x1FFFF) * 16 + fl];
    uint2 v3 = h4[(size_t)(unsigned)(r3 & 0x1FFFF) * 16 + fl];
    float n0 = __int_as_float((int)(r0 >> 32));
    float n1 = __int_as_float((int)(r1 >> 32));
    float n2 = __int_as_float((int)(r2 >> 32));
    float n3 = __int_as_float((int)(r3 >> 32));
    FMA4(n0, v0);
    FMA4(n1, v1);
    FMA4(n2, v2);
    FMA4(n3, v3);
  }
  for (; e + 8 <= end; e += 8) {
    long long r0 = pr[e + sub];
    long long r1 = pr[e + 4 + sub];
    uint2 v0 = h4[(size_t)(unsigned)(r0 & 0x1FFFF) * 16 + fl];
    uint2 v1 = h4[(size_t)(unsigned)(r1 & 0x1FFFF) * 16 + fl];
    float n0 = __int_as_float((int)(r0 >> 32));
    float n1 = __int_as_float((int)(r1 >> 32));
    FMA4(n0, v0);
    FMA4(n1, v1);
  }
  for (; e < end; e += 4) {
    int idx = e + sub;
    bool ok = idx < end;
    long long r0 = ok ? pr[idx] : 0;
    unsigned s = ok ? (unsigned)(r0 & 0x1FFFF) : (unsigned)wid;
    float n0 = ok ? __int_as_float((int)(r0 >> 32)) : 0.f;
    uint2 v0 = h4[(size_t)s * 16 + fl];
    FMA4(n0, v0);
  }
  if (sub == 0) {                                   // self term
    uint2 ov = h4[(size_t)wid * 16 + fl];
    FMA4(1.0f, ov);
  }
#pragma unroll
  for (int q = 0; q < 2; ++q) {
    ax[q] += __shfl_xor(ax[q], 16, 64); ay[q] += __shfl_xor(ay[q], 16, 64);
    ax[q] += __shfl_xor(ax[q], 32, 64); ay[q] += __shfl_xor(ay[q], 32, 64);
  }
  if (sub == 0 && fl < 10) {
    float di = dinv[wid];
    float4 bv = ((const float4*)b2)[fl];
    float4 o = make_float4(fmaf(di, ax[0], bv.x), fmaf(di, ay[0], bv.y),
                           fmaf(di, ax[1], bv.z), fmaf(di, ay[1], bv.w));
    *(float4*)(out + (size_t)wid * NC + fl * 4) = o;
  }
}

// ---------------- host launch ----------------

extern "C" void kernel_launch(void* const* d_in, const int* in_sizes, int n_in,
                              void* d_out, int out_size, void* d_ws, size_t ws_size,
                              hipStream_t stream) {
  const float* x  = (const float*)d_in[0];
  const int*   ei = (const int*)d_in[1];
  const float* ew = (const float*)d_in[2];
  const float* W1 = (const float*)d_in[3];
  const float* b1 = (const float*)d_in[4];
  const float* W2 = (const float*)d_in[5];
  const float* b2 = (const float*)d_in[6];
  float* out = (float*)d_out;
  const int* row = ei;
  const int* col = ei + NE;

  char* ws = (char*)d_ws;
  size_t o = 0;
  auto alloc = [&](size_t bytes) -> void* {
    void* p = ws + o;
    o += (bytes + 255) & ~(size_t)255;
    return p;
  };
  float* dinv    = (float*)alloc((size_t)NN * 4);
  int*   rowptr  = (int*)alloc((size_t)(NN + 1) * 4);
  int*   binfill = (int*)alloc(1024);
  int*   binptr  = (int*)alloc(1024);
  int2*  pair    = (int2*)alloc((size_t)NE * 8);
  unsigned short* Wfh = (unsigned short*)alloc((size_t)NF * NH * 2);
  unsigned short* Wfl = (unsigned short*)alloc((size_t)NF * NH * 2);
  unsigned short* hxb = (unsigned short*)alloc((size_t)NN * NH * 2);
  unsigned*       hb  = (unsigned*)alloc((size_t)NN * NH * 2);
  int2*  binned  = (int2*)alloc((size_t)NBIN * CAP * 8);
  unsigned short* h2b = (unsigned short*)hxb;   // hxb dead after k_agg1

  k_wconv<<<(NF * NH) / 256, 256, 0, stream>>>(W1, Wfh, Wfl, binfill);
  k_binA<<<(NE + EPB - 1) / EPB, 256, 0, stream>>>(row, col, ew, binfill, binned);
  k_binscan<<<1, 256, 0, stream>>>(binfill, binptr, rowptr);
  k_binB<<<NBIN, 256, 0, stream>>>(binfill, binptr, binned, pair, rowptr, dinv);
  k_gemm1<<<(NN + 63) / 64, 256, 0, stream>>>(x, Wfh, Wfl, dinv, hxb);
  k_agg1<<<(NN * 64) / 256, 256, 0, stream>>>(rowptr, pair, (const unsigned*)hxb, dinv, b1, hb);
  k_gemm2<<<(NN + 31) / 32, 256, 0, stream>>>(hb, W2, dinv, h2b);
  k_agg2<<<(NN * 64) / 256, 256, 0, stream>>>(rowptr, pair, (const unsigned*)h2b, dinv, b2, out);
}

// Round 12
// 386.487 us; speedup vs baseline: 1.1880x; 1.0386x over previous
//
#include <hip/hip_runtime.h>

#define NN 100000
#define NE 3200000
#define NF 512
#define NH 128
#define NC 40
#define NBIN 196      // ceil(NN/512)
#define BINW 512
#define CAP  20480    // per-bin capacity (mean 16327, +32 sigma)
#define EPB  4096     // edges per binA block

typedef __attribute__((ext_vector_type(8))) short bfrag;
typedef __attribute__((ext_vector_type(4))) float f32x4;
typedef __attribute__((ext_vector_type(8))) unsigned short u16x8;

static __device__ __forceinline__ unsigned short f2bf(float x) {
  unsigned u = __float_as_uint(x);
  u += 0x7FFF + ((u >> 16) & 1);          // RNE
  return (unsigned short)(u >> 16);
}
static __device__ __forceinline__ float bf2f(unsigned short b) {
  return __uint_as_float(((unsigned)b) << 16);
}
static __device__ __forceinline__ float bflo(unsigned u) { return __uint_as_float(u << 16); }
static __device__ __forceinline__ float bfhi(unsigned u) { return __uint_as_float(u & 0xFFFF0000u); }

// ---------------- W1 -> split-bf16 fragment layout; block 0 also zeros binfill ----------------

__global__ __launch_bounds__(256) void k_wconv(const float* __restrict__ W1,
                                               unsigned short* __restrict__ Wfh,
                                               unsigned short* __restrict__ Wfl,
                                               int* __restrict__ binfill) {
  if (blockIdx.x == 0 && threadIdx.x < NBIN) binfill[threadIdx.x] = 0;
  int i = blockIdx.x * 256 + threadIdx.x;
  int k = i >> 7, n = i & 127;
  float w = W1[i];
  unsigned short hi = f2bf(w);
  unsigned short lo = f2bf(w - bf2f(hi));
  int idx = ((k >> 3) * 128 + n) * 8 + (k & 7);
  Wfh[idx] = hi; Wfl[idx] = lo;
}

// ---------------- Pass A: bin edges by col>>9, LDS histogram + block-level reservation ----------------

__global__ __launch_bounds__(256) void k_binA(const int* __restrict__ row, const int* __restrict__ col,
                                              const float* __restrict__ w,
                                              int* __restrict__ binfill, int2* __restrict__ binned) {
  __shared__ int hist[NBIN];
  __shared__ int base[NBIN];
  int t = threadIdx.x;
  int eb = blockIdx.x * EPB;
  for (int i = t; i < NBIN; i += 256) hist[i] = 0;
  __syncthreads();
  int rk[16], bn[16], sr[16]; float wv[16];
#pragma unroll
  for (int j = 0; j < 16; ++j) {
    int e = eb + t + j * 256;
    if (e < NE) {
      int c = __builtin_nontemporal_load(col + e);
      bn[j] = c >> 9;
      sr[j] = __builtin_nontemporal_load(row + e) | ((c & 511) << 17);
      wv[j] = __builtin_nontemporal_load(w + e);
      rk[j] = atomicAdd(&hist[bn[j]], 1);
    } else bn[j] = -1;
  }
  __syncthreads();
  if (t < NBIN) { int hv = hist[t]; base[t] = hv ? atomicAdd(&binfill[t], hv) : 0; }
  __syncthreads();
#pragma unroll
  for (int j = 0; j < 16; ++j) {
    if (bn[j] >= 0) {
      int pos = base[bn[j]] + rk[j];
      if (pos < CAP) binned[(size_t)bn[j] * CAP + pos] = make_int2(sr[j], __float_as_int(wv[j]));
    }
  }
}

// ---------------- scan bin counts -> binptr; rowptr[NN]=NE ----------------

__global__ __launch_bounds__(256) void k_binscan(const int* __restrict__ binfill,
                                                 int* __restrict__ binptr, int* __restrict__ rowptr) {
  __shared__ int sm[256];
  int t = threadIdx.x;
  sm[t] = (t < NBIN) ? binfill[t] : 0;
  __syncthreads();
  for (int off = 1; off < 256; off <<= 1) {
    int a = (t >= off) ? sm[t - off] : 0;
    __syncthreads();
    sm[t] += a;
    __syncthreads();
  }
  if (t <= NBIN) binptr[t] = (t == 0) ? 0 : sm[t - 1];
  if (t == 0) rowptr[NN] = NE;
}

// ---------------- Pass B: per-bin CSR build via LDS atomics (no global atomics) ----------------

__global__ __launch_bounds__(256) void k_binB(const int* __restrict__ binfill, const int* __restrict__ binptr,
                                              const int2* __restrict__ binned, int2* __restrict__ pair,
                                              int* __restrict__ rowptr, float* __restrict__ dinv) {
  __shared__ unsigned long long pk[BINW];     // count<<42 | fixed-point weight sum
  __shared__ unsigned short lrank[CAP];
  __shared__ int lptr[BINW];
  __shared__ int sm[256];
  int t = threadIdx.x;
  int bin = blockIdx.x;
  int cnt = binfill[bin]; if (cnt > CAP) cnt = CAP;
  int bb = binptr[bin];
  pk[t] = 0ULL; pk[t + 256] = 0ULL;
  __syncthreads();
  const int2* src = binned + (size_t)bin * CAP;
  for (int i = t; i < cnt; i += 256) {
    int2 r = src[i];
    int lc = (unsigned)r.x >> 17;
    unsigned long long fw = (unsigned long long)(unsigned)(__int_as_float(r.y) * 16777216.0f + 0.5f);
    unsigned long long old = atomicAdd(&pk[lc], (1ULL << 42) | fw);
    lrank[i] = (unsigned short)(old >> 42);
  }
  __syncthreads();
  int c0 = (int)(pk[2 * t] >> 42), c1 = (int)(pk[2 * t + 1] >> 42);
  sm[t] = c0 + c1;
  __syncthreads();
  for (int off = 1; off < 256; off <<= 1) {
    int a = (t >= off) ? sm[t - off] : 0;
    __syncthreads();
    sm[t] += a;
    __syncthreads();
  }
  int excl = (t == 0) ? 0 : sm[t - 1];
  lptr[2 * t] = excl;
  lptr[2 * t + 1] = excl + c0;
  int n0 = bin * BINW + 2 * t;
  if (n0 < NN) {
    rowptr[n0] = bb + excl;
    float d = (float)(pk[2 * t] & 0x3FFFFFFFFFFULL) * (1.0f / 16777216.0f) + 1.0f;
    dinv[n0] = rsqrtf(d);
  }
  if (n0 + 1 < NN) {
    rowptr[n0 + 1] = bb + excl + c0;
    float d = (float)(pk[2 * t + 1] & 0x3FFFFFFFFFFULL) * (1.0f / 16777216.0f) + 1.0f;
    dinv[n0 + 1] = rsqrtf(d);
  }
  __syncthreads();
  for (int i = t; i < cnt; i += 256) {
    int2 r = src[i];
    int lc = (unsigned)r.x >> 17;
    int pos = bb + lptr[lc] + (int)lrank[i];
    pair[pos] = make_int2(r.x & 0x1FFFF, r.y);   // (src, raw w) — dinv folded into activations
  }
}

// ---------------- GEMM1: hx' = dinv[r] * (x @ W1); bf16 MFMA 2-term ----------------
// BM=64 tile; CONTIGUOUS-LANE A staging: row = t>>2, k-chunk = (t&3)*8
// -> one wave-load touches 16 dense 64B lines instead of 64 strided lines.

__global__ __launch_bounds__(256) void k_gemm1(const float* __restrict__ X,
                                               const unsigned short* __restrict__ Wfh,
                                               const unsigned short* __restrict__ Wfl,
                                               const float* __restrict__ dinv,
                                               unsigned short* __restrict__ HXb) {
  __shared__ unsigned short Ah[2048], Bh[4096], Bl[4096];   // 20 KB
  int t = threadIdx.x;
  int lane = t & 63;
  int wid = t >> 6;
  int m0 = blockIdx.x * 64;
  int srow = t >> 2;          // staging row (0..63): 4 consecutive threads per row
  int quad = t & 3;           // k-chunk (8 f32 each)
  const float* xrow = X + (size_t)(m0 + srow) * NF + quad * 8;
  bool mok = (m0 + srow) < NN;
  int wm = wid >> 1, wn = wid & 1;
  int mb = wm * 32, nb = wn * 64;
  int fr = lane & 15, fg = lane >> 4;

  f32x4 acc[2][4];
#pragma unroll
  for (int i = 0; i < 2; ++i)
#pragma unroll
    for (int j = 0; j < 4; ++j) acc[i][j] = (f32x4)0.0f;

  for (int ks = 0; ks < 16; ++ks) {
    // ---- issue global loads (B slabs + 8 f32 of A per thread, lane-contiguous)
    const u16x8* sh = (const u16x8*)(Wfh + (size_t)ks * 4096);
    const u16x8* sl = (const u16x8*)(Wfl + (size_t)ks * 4096);
    u16x8 b0 = sh[t], b1 = sh[t + 256];
    u16x8 c0 = sl[t], c1 = sl[t + 256];
    float4 xv0 = mok ? *(const float4*)(xrow + ks * 32)     : make_float4(0.f, 0.f, 0.f, 0.f);
    float4 xv1 = mok ? *(const float4*)(xrow + ks * 32 + 4) : make_float4(0.f, 0.f, 0.f, 0.f);
    // ---- convert A (hi only) and write LDS: layout [kb=quad][64 rows][8]
#pragma unroll
    for (int q = 0; q < 2; ++q) {
      float4 xq = q ? xv1 : xv0;
      float f[4] = {xq.x, xq.y, xq.z, xq.w};
      unsigned short h[4];
#pragma unroll
      for (int j = 0; j < 4; ++j) h[j] = f2bf(f[j]);
      int base = (quad * 64 + srow) * 8 + q * 4;
      uint2 hv = make_uint2((unsigned)h[0] | ((unsigned)h[1] << 16),
                            (unsigned)h[2] | ((unsigned)h[3] << 16));
      *(uint2*)&Ah[base] = hv;
    }
    ((u16x8*)Bh)[t] = b0; ((u16x8*)Bh)[t + 256] = b1;
    ((u16x8*)Bl)[t] = c0; ((u16x8*)Bl)[t + 256] = c1;
    __syncthreads();
    // ---- fragments from LDS
    bfrag ah[2], bh[4], bl[4];
#pragma unroll
    for (int mi = 0; mi < 2; ++mi)
      ah[mi] = *(bfrag*)&Ah[(fg * 64 + mb + mi * 16 + fr) * 8];
#pragma unroll
    for (int nt = 0; nt < 4; ++nt) {
      int idx = (fg * 128 + nb + nt * 16 + fr) * 8;
      bh[nt] = *(bfrag*)&Bh[idx];
      bl[nt] = *(bfrag*)&Bl[idx];
    }
#pragma unroll
    for (int mi = 0; mi < 2; ++mi)
#pragma unroll
      for (int nt = 0; nt < 4; ++nt) {
        acc[mi][nt] = __builtin_amdgcn_mfma_f32_16x16x32_bf16(ah[mi], bh[nt], acc[mi][nt], 0, 0, 0);
        acc[mi][nt] = __builtin_amdgcn_mfma_f32_16x16x32_bf16(ah[mi], bl[nt], acc[mi][nt], 0, 0, 0);
      }
    __syncthreads();
  }
  // ---- epilogue: D row = m0 + mb + mi*16 + fg*4 + q, col = nb + nt*16 + fr
#pragma unroll
  for (int mi = 0; mi < 2; ++mi) {
    int rb = m0 + mb + mi * 16 + fg * 4;
#pragma unroll
    for (int q = 0; q < 4; ++q) {
      int r = rb + q;
      if (r < NN) {
        float dv = dinv[r];
#pragma unroll
        for (int nt = 0; nt < 4; ++nt) {
          int c = nb + nt * 16 + fr;
          __builtin_nontemporal_store(f2bf(dv * acc[mi][nt][q]), HXb + (size_t)r * NH + c);
        }
      }
    }
  }
}

// ---------------- agg1: 16 lanes/row, 4 edges/step, 16-edge main loop ----------------
// h = relu(dinv_c*(sum_e w*hx'[src] + hx'[c]) + b1)

#define FMA8(n, v)                                            \
  { unsigned uu[4] = {(v).x, (v).y, (v).z, (v).w};            \
    _Pragma("unroll")                                         \
    for (int q = 0; q < 4; ++q) {                             \
      ax[q] = fmaf((n), bflo(uu[q]), ax[q]);                  \
      ay[q] = fmaf((n), bfhi(uu[q]), ay[q]);                  \
    } }

__global__ __launch_bounds__(256) void k_agg1(const int* __restrict__ rowptr, const int2* __restrict__ pair,
                                              const unsigned* __restrict__ hxb, const float* __restrict__ dinv,
                                              const float* __restrict__ b1, unsigned* __restrict__ hb) {
  int wid = (blockIdx.x * 256 + threadIdx.x) >> 6;
  int lane = threadIdx.x & 63;
  if (wid >= NN) return;
  int sub = lane >> 4, fl = lane & 15;
  int beg = rowptr[wid], end = rowptr[wid + 1];
  const uint4* hx4 = (const uint4*)hxb;            // row = 16 uint4 (256 B)
  const long long* pr = (const long long*)pair;
  float ax[4] = {0.f, 0.f, 0.f, 0.f}, ay[4] = {0.f, 0.f, 0.f, 0.f};
  int e = beg;
  for (; e + 16 <= end; e += 16) {
    long long r0 = pr[e + sub];
    long long r1 = pr[e + 4 + sub];
    long long r2 = pr[e + 8 + sub];
    long long r3 = pr[e + 12 + sub];
    uint4 v0 = hx4[(size_t)(unsigned)(r0 & 0x1FFFF) * 16 + fl];
    uint4 v1 = hx4[(size_t)(unsigned)(r1 & 0x1FFFF) * 16 + fl];
    uint4 v2 = hx4[(size_t)(unsigned)(r2 & 0x1FFFF) * 16 + fl];
    uint4 v3 = hx4[(size_t)(unsigned)(r3 & 0x1FFFF) * 16 + fl];
    float n0 = __int_as_float((int)(r0 >> 32));
    float n1 = __int_as_float((int)(r1 >> 32));
    float n2 = __int_as_float((int)(r2 >> 32));
    float n3 = __int_as_float((int)(r3 >> 32));
    FMA8(n0, v0);
    FMA8(n1, v1);
    FMA8(n2, v2);
    FMA8(n3, v3);
  }
  for (; e + 8 <= end; e += 8) {
    long long r0 = pr[e + sub];
    long long r1 = pr[e + 4 + sub];
    uint4 v0 = hx4[(size_t)(unsigned)(r0 & 0x1FFFF) * 16 + fl];
    uint4 v1 = hx4[(size_t)(unsigned)(r1 & 0x1FFFF) * 16 + fl];
    float n0 = __int_as_float((int)(r0 >> 32));
    float n1 = __int_as_float((int)(r1 >> 32));
    FMA8(n0, v0);
    FMA8(n1, v1);
  }
  for (; e < end; e += 4) {
    int idx = e + sub;
    bool ok = idx < end;
    long long r0 = ok ? pr[idx] : 0;
    unsigned s = ok ? (unsigned)(r0 & 0x1FFFF) : (unsigned)wid;
    float n0 = ok ? __int_as_float((int)(r0 >> 32)) : 0.f;
    uint4 v0 = hx4[(size_t)s * 16 + fl];
    FMA8(n0, v0);
  }
  if (sub == 0) {                                   // self term, weight 1
    uint4 ov = hx4[(size_t)wid * 16 + fl];
    FMA8(1.0f, ov);
  }
#pragma unroll
  for (int q = 0; q < 4; ++q) {
    ax[q] += __shfl_xor(ax[q], 16, 64); ay[q] += __shfl_xor(ay[q], 16, 64);
    ax[q] += __shfl_xor(ax[q], 32, 64); ay[q] += __shfl_xor(ay[q], 32, 64);
  }
  if (sub == 0) {
    float di = dinv[wid];
    float4 bA = ((const float4*)b1)[fl * 2];
    float4 bB = ((const float4*)b1)[fl * 2 + 1];
    float bxs[4] = {bA.x, bA.z, bB.x, bB.z};
    float bys[4] = {bA.y, bA.w, bB.y, bB.w};
    unsigned o[4];
#pragma unroll
    for (int q = 0; q < 4; ++q) {
      float rx = fmaxf(fmaf(di, ax[q], bxs[q]), 0.f);
      float ry = fmaxf(fmaf(di, ay[q], bys[q]), 0.f);
      o[q] = (unsigned)f2bf(rx) | ((unsigned)f2bf(ry) << 16);
    }
    ((uint4*)hb)[(size_t)wid * 16 + fl] = make_uint4(o[0], o[1], o[2], o[3]);
  }
}

// ---------------- GEMM2: h2' = dinv[r] * (h @ W2)   [bf16 in, bf16-padded64 out] ----------------

__global__ __launch_bounds__(256) void k_gemm2(const unsigned* __restrict__ hb, const float* __restrict__ W2,
                                               const float* __restrict__ dinv,
                                               unsigned short* __restrict__ H2b) {
  __shared__ float Hs[32][132];
  __shared__ float Ws[NH * NC];
  int t = threadIdx.x;
  int m0 = blockIdx.x * 32;
  {
    int r = t >> 3, cb = (t & 7) * 8;
    int rowi = m0 + r;
    if (rowi < NN) {
      uint4 a = *(const uint4*)(hb + (size_t)rowi * 64 + cb);
      uint4 b = *(const uint4*)(hb + (size_t)rowi * 64 + cb + 4);
      unsigned u[8] = {a.x, a.y, a.z, a.w, b.x, b.y, b.z, b.w};
#pragma unroll
      for (int j = 0; j < 8; ++j) {
        Hs[r][cb * 2 + j * 2]     = bflo(u[j]);
        Hs[r][cb * 2 + j * 2 + 1] = bfhi(u[j]);
      }
    } else {
#pragma unroll
      for (int j = 0; j < 16; ++j) Hs[r][cb * 2 + j] = 0.f;
    }
  }
  for (int i = t; i < NH * NC; i += 256) Ws[i] = W2[i];
  __syncthreads();
  int r = t >> 3, c0 = (t & 7) * 5;
  float acc[5] = {0.f, 0.f, 0.f, 0.f, 0.f};
#pragma unroll 4
  for (int k = 0; k < NH; ++k) {
    float hv = Hs[r][k];
#pragma unroll
    for (int j = 0; j < 5; ++j) acc[j] = fmaf(hv, Ws[k * NC + c0 + j], acc[j]);
  }
  int rowi = m0 + r;
  if (rowi < NN) {
    float dv = dinv[rowi];
#pragma unroll
    for (int j = 0; j < 5; ++j)
      __builtin_nontemporal_store(f2bf(dv * acc[j]), H2b + (size_t)rowi * 64 + c0 + j);
    int prr = t & 7;
    if (prr < 3) {
#pragma unroll
      for (int j = 0; j < 8; ++j)
        __builtin_nontemporal_store((unsigned short)0, H2b + (size_t)rowi * 64 + 40 + prr * 8 + j);
    }
  }
}

// ---------------- agg2: 16 lanes/row, 4 edges/step, 16-edge main loop ----------------
// out = dinv_c*(sum_e w*h2'[src] + h2'[c]) + b2

#define FMA4(n, v)                                            \
  { unsigned uu[2] = {(v).x, (v).y};                          \
    _Pragma("unroll")                                         \
    for (int q = 0; q < 2; ++q) {                             \
      ax[q] = fmaf((n), bflo(uu[q]), ax[q]);                  \
      ay[q] = fmaf((n), bfhi(uu[q]), ay[q]);                  \
    } }

__global__ __launch_bounds__(256) void k_agg2(const int* __restrict__ rowptr, const int2* __restrict__ pair,
                                              const unsigned* __restrict__ h2u,
                                              const float* __restrict__ dinv,
                                              const float* __restrict__ b2, float* __restrict__ out) {
  int wid = (blockIdx.x * 256 + threadIdx.x) >> 6;
  int lane = threadIdx.x & 63;
  if (wid >= NN) return;
  int sub = lane >> 4, fl = lane & 15;
  int beg = rowptr[wid], end = rowptr[wid + 1];
  const uint2* h4 = (const uint2*)h2u;              // row = 16 uint2 (128 B)
  const long long* pr = (const long long*)pair;
  float ax[2] = {0.f, 0.f}, ay[2] = {0.f, 0.f};
  int e = beg;
  for (; e + 16 <= end; e += 16) {
    long long r0 = pr[e + sub];
    long long r1 = pr[e + 4 + sub];
    long long r2 = pr[e + 8 + sub];
    long long r3 = pr[e + 12 + sub];
    uint2 v0 = h4[(size_t)(unsigned)(r0 & 0x1FFFF) * 16 + fl];
    uint2 v1 = h4[(size_t)(unsigned)(r1 & 0x1FFFF) * 16 + fl];
    uint2 v2 = h4[(size_t)(unsigned)(r2 & 0x1FFFF) * 16 + fl];
    uint2 v3 = h4[(size_t)(unsigned)(r3 & 0x1FFFF) * 16 + fl];
    float n0 = __int_as_float((int)(r0 >> 32));
    float n1 = __int_as_float((int)(r1 >> 32));
    float n2 = __int_as_float((int)(r2 >> 32));
    float n3 = __int_as_float((int)(r3 >> 32));
    FMA4(n0, v0);
    FMA4(n1, v1);
    FMA4(n2, v2);
    FMA4(n3, v3);
  }
  for (; e + 8 <= end; e += 8) {
    long long r0 = pr[e + sub];
    long long r1 = pr[e + 4 + sub];
    uint2 v0 = h4[(size_t)(unsigned)(r0 & 0x1FFFF) * 16 + fl];
    uint2 v1 = h4[(size_t)(unsigned)(r1 & 0x1FFFF) * 16 + fl];
    float n0 = __int_as_float((int)(r0 >> 32));
    float n1 = __int_as_float((int)(r1 >> 32));
    FMA4(n0, v0);
    FMA4(n1, v1);
  }
  for (; e < end; e += 4) {
    int idx = e + sub;
    bool ok = idx < end;
    long long r0 = ok ? pr[idx] : 0;
    unsigned s = ok ? (unsigned)(r0 & 0x1FFFF) : (unsigned)wid;
    float n0 = ok ? __int_as_float((int)(r0 >> 32)) : 0.f;
    uint2 v0 = h4[(size_t)s * 16 + fl];
    FMA4(n0, v0);
  }
  if (sub == 0) {                                   // self term
    uint2 ov = h4[(size_t)wid * 16 + fl];
    FMA4(1.0f, ov);
  }
#pragma unroll
  for (int q = 0; q < 2; ++q) {
    ax[q] += __shfl_xor(ax[q], 16, 64); ay[q] += __shfl_xor(ay[q], 16, 64);
    ax[q] += __shfl_xor(ax[q], 32, 64); ay[q] += __shfl_xor(ay[q], 32, 64);
  }
  if (sub == 0 && fl < 10) {
    float di = dinv[wid];
    float4 bv = ((const float4*)b2)[fl];
    float4 o = make_float4(fmaf(di, ax[0], bv.x), fmaf(di, ay[0], bv.y),
                           fmaf(di, ax[1], bv.z), fmaf(di, ay[1], bv.w));
    *(float4*)(out + (size_t)wid * NC + fl * 4) = o;
  }
}

// ---------------- host launch ----------------

extern "C" void kernel_launch(void* const* d_in, const int* in_sizes, int n_in,
                              void* d_out, int out_size, void* d_ws, size_t ws_size,
                              hipStream_t stream) {
  const float* x  = (const float*)d_in[0];
  const int*   ei = (const int*)d_in[1];
  const float* ew = (const float*)d_in[2];
  const float* W1 = (const float*)d_in[3];
  const float* b1 = (const float*)d_in[4];
  const float* W2 = (const float*)d_in[5];
  const float* b2 = (const float*)d_in[6];
  float* out = (float*)d_out;
  const int* row = ei;
  const int* col = ei + NE;

  char* ws = (char*)d_ws;
  size_t o = 0;
  auto alloc = [&](size_t bytes) -> void* {
    void* p = ws + o;
    o += (bytes + 255) & ~(size_t)255;
    return p;
  };
  float* dinv    = (float*)alloc((size_t)NN * 4);
  int*   rowptr  = (int*)alloc((size_t)(NN + 1) * 4);
  int*   binfill = (int*)alloc(1024);
  int*   binptr  = (int*)alloc(1024);
  int2*  pair    = (int2*)alloc((size_t)NE * 8);
  unsigned short* Wfh = (unsigned short*)alloc((size_t)NF * NH * 2);
  unsigned short* Wfl = (unsigned short*)alloc((size_t)NF * NH * 2);
  unsigned short* hxb = (unsigned short*)alloc((size_t)NN * NH * 2);
  unsigned*       hb  = (unsigned*)alloc((size_t)NN * NH * 2);
  int2*  binned  = (int2*)alloc((size_t)NBIN * CAP * 8);
  unsigned short* h2b = (unsigned short*)hxb;   // hxb dead after k_agg1

  k_wconv<<<(NF * NH) / 256, 256, 0, stream>>>(W1, Wfh, Wfl, binfill);
  k_binA<<<(NE + EPB - 1) / EPB, 256, 0, stream>>>(row, col, ew, binfill, binned);
  k_binscan<<<1, 256, 0, stream>>>(binfill, binptr, rowptr);
  k_binB<<<NBIN, 256, 0, stream>>>(binfill, binptr, binned, pair, rowptr, dinv);
  k_gemm1<<<(NN + 63) / 64, 256, 0, stream>>>(x, Wfh, Wfl, dinv, hxb);
  k_agg1<<<(NN * 64) / 256, 256, 0, stream>>>(rowptr, pair, (const unsigned*)hxb, dinv, b1, hb);
  k_gemm2<<<(NN + 31) / 32, 256, 0, stream>>>(hb, W2, dinv, h2b);
  k_agg2<<<(NN * 64) / 256, 256, 0, stream>>>(rowptr, pair, (const unsigned*)h2b, dinv, b2, out);
}